// Round 4
// baseline (38951.819 us; speedup 1.0000x reference)
//
#include <hip/hip_runtime.h>

// LSTM: S=4096, I=64, H=1024, O=1, fp32.
// Persistent cooperative kernel, 256 blocks x 256 threads.
//   block b, wave w (0..3): owns h-index j = 4b+w
//   lane group grp = lane>>4: gate q = grp, row r = q*1024 + j
//   sub-lane sl = lane&15: handles h elements 64c+4sl..+3, c=0..15, + x[4sl..+3]
// Round-2/3 lesson: compiler refuses to keep 68 weight floats in VGPRs
// (VGPR_Count=52 both rounds; ~18 MB/step W_hh re-read from L3 = the whole
// runtime). Fix: stage weights in LDS once — structural residency, immune to
// the per-step device-acquire L2 invalidate and to RA heuristics.
// LDS: wlds4[c*256+t] float4 (c=0..16: 16 W_hh quads + 1 W_ih quad) = 68 KB,
// lane-contiguous b128 reads (same pattern as hs4[t] staging: 0 conflicts).
// Barrier: per-block monotonic flags (release store) + one-wave poll-all +
// device acquire fence (round 3, worked correctly).

#define SEQ_LEN 4096
#define HID 1024
#define NBLK 256
#define TPB 256

__device__ __forceinline__ float fast_sigmoid(float x) {
    return __builtin_amdgcn_rcpf(1.0f + __builtin_amdgcn_exp2f(-1.4426950408889634f * x));
}
__device__ __forceinline__ float fast_tanh(float x) {
    return fmaf(-2.0f, __builtin_amdgcn_rcpf(1.0f + __builtin_amdgcn_exp2f(2.8853900817779268f * x)), 1.0f);
}
__device__ __forceinline__ unsigned umin4(unsigned a, unsigned b, unsigned c, unsigned d) {
    unsigned x = a < b ? a : b;
    unsigned y = c < d ? c : d;
    return x < y ? x : y;
}

// ws layout (floats): [0..1023] hbuf0, [1024..2047] hbuf1, then u32 flags[256]
__global__ void lstm_init_kernel(float* ws) {
    int t = threadIdx.x;
    ((float4*)ws)[t] = make_float4(0.f, 0.f, 0.f, 0.f);   // hbuf0 = h_0 = 0
    ((unsigned*)(ws + 2 * HID))[t] = 0u;                  // flags = 0
}

__global__ __launch_bounds__(TPB, 1) void lstm_persistent_kernel(
    const float* __restrict__ input,   // [4096][64]
    const float* __restrict__ W_ih,    // [4096][64]
    const float* __restrict__ W_hh,    // [4096][1024]
    const float* __restrict__ b_ih,    // [4096]
    const float* __restrict__ b_hh,    // [4096]
    const float* __restrict__ W_lin,   // [1][1024]
    const float* __restrict__ b_lin,   // [1]
    float* __restrict__ out,           // [1]
    float* __restrict__ ws)
{
    const int t   = threadIdx.x;
    const int b   = blockIdx.x;
    const int w   = t >> 6;      // wave in block
    const int l   = t & 63;      // lane
    const int grp = l >> 4;      // gate q
    const int sl  = l & 15;      // sub-lane within gate group
    const int j   = 4 * b + w;   // owned h index
    const int row = grp * HID + j;

    float* hbuf0 = ws;
    float* hbuf1 = ws + HID;
    unsigned* flags = (unsigned*)(ws + 2 * HID);

    __shared__ float4 wlds4[17 * TPB];   // 68 KB: thread t's 17 weight quads
    __shared__ float  hs[HID + 64];      // h (1024) then x_s (64)
    __shared__ float  red[4];
    float4* hs4 = (float4*)hs;

    // ---- stage this block's weight slice into LDS (once) ----
    {
        const float4* Whh4 = (const float4*)(W_hh + (size_t)row * HID);
        #pragma unroll
        for (int c = 0; c < 16; ++c)
            wlds4[c * TPB + t] = Whh4[sl + 16 * c];     // W_hh[row][64c+4sl..+3]
        wlds4[16 * TPB + t] = ((const float4*)(W_ih + (size_t)row * 64))[sl];
    }

    float bias[4];
    #pragma unroll
    for (int q = 0; q < 4; ++q) bias[q] = b_ih[q * HID + j] + b_hh[q * HID + j];

    const float4* xin4 = (const float4*)input;

    float c_state = 0.0f;
    __syncthreads();   // weights staged

    for (int s = 0; s < SEQ_LEN; ++s) {
        const float* hread = (s & 1) ? hbuf1 : hbuf0;
        float* hwrite      = (s & 1) ? hbuf0 : hbuf1;

        // stage h_s and x_s into LDS (coalesced 4KB + 256B)
        float4 hv = ((const float4*)hread)[t];
        hs4[t] = hv;
        if (t < 16) hs4[256 + t] = xin4[s * 16 + t];
        __syncthreads();

        // 68 FMAs: weights from LDS (b128, lane-contiguous, conflict-free),
        // h from LDS (16 distinct addrs x 4-way broadcast, conflict-free).
        float acc = 0.0f;
        #pragma unroll
        for (int c = 0; c < 16; ++c) {
            float4 wv = wlds4[c * TPB + t];
            float4 h4 = hs4[16 * c + sl];
            acc = fmaf(wv.x, h4.x, acc);
            acc = fmaf(wv.y, h4.y, acc);
            acc = fmaf(wv.z, h4.z, acc);
            acc = fmaf(wv.w, h4.w, acc);
        }
        {
            float4 wv = wlds4[16 * TPB + t];
            float4 x4 = hs4[256 + sl];
            acc = fmaf(wv.x, x4.x, acc);
            acc = fmaf(wv.y, x4.y, acc);
            acc = fmaf(wv.z, x4.z, acc);
            acc = fmaf(wv.w, x4.w, acc);
        }

        // reduce across the 16 lanes of the gate group
        acc += __shfl_xor(acc, 1);
        acc += __shfl_xor(acc, 2);
        acc += __shfl_xor(acc, 4);
        acc += __shfl_xor(acc, 8);

        // gather the 4 gate preactivations (uniform within each group)
        float gi = __shfl(acc, 0)  + bias[0];
        float gf = __shfl(acc, 16) + bias[1];
        float gg = __shfl(acc, 32) + bias[2];
        float go = __shfl(acc, 48) + bias[3];

        float ig = fast_sigmoid(gi);
        float fg = fast_sigmoid(gf);
        float cg = fast_tanh(gg);
        float og = fast_sigmoid(go);
        c_state  = fmaf(fg, c_state, ig * cg);
        float hn = og * fast_tanh(c_state);

        if (l == 0) hwrite[j] = hn;   // one float per wave
        __syncthreads();              // drains vmcnt(0): all 4 waves' h-stores visible

        // ---- grid barrier: per-block flag (release) + one-wave poll + acquire fence
        if (t == 0)
            __hip_atomic_store(&flags[b], (unsigned)(s + 1),
                               __ATOMIC_RELEASE, __HIP_MEMORY_SCOPE_AGENT);
        if (t < 64) {
            const unsigned target = (unsigned)(s + 1);
            unsigned m;
            do {
                unsigned f0 = __hip_atomic_load(&flags[t      ], __ATOMIC_RELAXED, __HIP_MEMORY_SCOPE_AGENT);
                unsigned f1 = __hip_atomic_load(&flags[t +  64], __ATOMIC_RELAXED, __HIP_MEMORY_SCOPE_AGENT);
                unsigned f2 = __hip_atomic_load(&flags[t + 128], __ATOMIC_RELAXED, __HIP_MEMORY_SCOPE_AGENT);
                unsigned f3 = __hip_atomic_load(&flags[t + 192], __ATOMIC_RELAXED, __HIP_MEMORY_SCOPE_AGENT);
                m = umin4(f0, f1, f2, f3);
            } while (!__all(m >= target));
            // relaxed loads observed all release stores -> acquire fence synchronizes
            __scoped_atomic_thread_fence(__ATOMIC_ACQUIRE, __MEMORY_SCOPE_DEVICE);
        }
        __syncthreads();
    }

    // final projection: out = h_4096 . W_lin + b_lin  (h_4096 in hbuf0)
    if (b == 0) {
        float4 hv = ((const float4*)hbuf0)[t];
        float4 wl = ((const float4*)W_lin)[t];
        float p = hv.x * wl.x + hv.y * wl.y + hv.z * wl.z + hv.w * wl.w;
        #pragma unroll
        for (int m = 32; m >= 1; m >>= 1) p += __shfl_xor(p, m);
        if (l == 0) red[w] = p;
        __syncthreads();
        if (t == 0) out[0] = red[0] + red[1] + red[2] + red[3] + b_lin[0];
    }
}

extern "C" void kernel_launch(void* const* d_in, const int* in_sizes, int n_in,
                              void* d_out, int out_size, void* d_ws, size_t ws_size,
                              hipStream_t stream) {
    const float* input = (const float*)d_in[0];
    const float* W_ih  = (const float*)d_in[1];
    const float* W_hh  = (const float*)d_in[2];
    const float* b_ih  = (const float*)d_in[3];
    const float* b_hh  = (const float*)d_in[4];
    const float* W_lin = (const float*)d_in[5];
    const float* b_lin = (const float*)d_in[6];
    float* out = (float*)d_out;
    float* ws  = (float*)d_ws;

    hipLaunchKernelGGL(lstm_init_kernel, dim3(1), dim3(256), 0, stream, ws);

    void* args[] = { (void*)&input, (void*)&W_ih, (void*)&W_hh, (void*)&b_ih,
                     (void*)&b_hh, (void*)&W_lin, (void*)&b_lin, (void*)&out, (void*)&ws };
    (void)hipLaunchCooperativeKernel((void*)lstm_persistent_kernel, dim3(NBLK), dim3(TPB),
                                     args, 0, stream);
}

// Round 5
// 11317.292 us; speedup vs baseline: 3.4418x; 3.4418x over previous
//
#include <hip/hip_runtime.h>

// LSTM: S=4096, I=64, H=1024, O=1, fp32.
// Persistent cooperative kernel, 256 blocks x 256 threads, weights in LDS.
// Round 2-4 lesson: ~9.5 us/step was NOT weight traffic (hbm_bytes ~300MB) —
// it was the agent-scope release/acquire machinery (buffer_wbl2 + buffer_inv
// per step per block) plus the forced L2 misses. This round: ZERO fences.
// h exchange via tagged 8-byte slots {tag:32|h_bits:32}, relaxed agent-scope
// atomic store/load (naturally atomic word => tag==s proves value is h_s).
// Tagged double buffer (even/odd step): producer writes tag T only after
// reading all tag T-1 => all blocks finished tag T-2 reads => buffer free.
// Intra-block: hs double-buffered in LDS, ONE __syncthreads per step.

#define SEQ_LEN 4096
#define HID 1024
#define NBLK 256
#define TPB 256

__device__ __forceinline__ float fast_sigmoid(float x) {
    return __builtin_amdgcn_rcpf(1.0f + __builtin_amdgcn_exp2f(-1.4426950408889634f * x));
}
__device__ __forceinline__ float fast_tanh(float x) {
    return fmaf(-2.0f, __builtin_amdgcn_rcpf(1.0f + __builtin_amdgcn_exp2f(2.8853900817779268f * x)), 1.0f);
}

// ws: unsigned long long slots[2][1024]. {tag<<32 | fp32 bits}.
// Init zero: buffer0 tag0/val0 == h_0 (correct); buffer1 expects odd tags.
__global__ void lstm_init_kernel(unsigned long long* ws) {
    int t = threadIdx.x;
    #pragma unroll
    for (int k = 0; k < 8; ++k) ws[t + 256 * k] = 0ull;
}

__global__ __launch_bounds__(TPB, 1) void lstm_persistent_kernel(
    const float* __restrict__ input,   // [4096][64]
    const float* __restrict__ W_ih,    // [4096][64]
    const float* __restrict__ W_hh,    // [4096][1024]
    const float* __restrict__ b_ih,    // [4096]
    const float* __restrict__ b_hh,    // [4096]
    const float* __restrict__ W_lin,   // [1][1024]
    const float* __restrict__ b_lin,   // [1]
    float* __restrict__ out,           // [1]
    unsigned long long* __restrict__ ws)
{
    const int t   = threadIdx.x;
    const int b   = blockIdx.x;
    const int w   = t >> 6;      // wave in block
    const int l   = t & 63;      // lane
    const int grp = l >> 4;      // gate q
    const int sl  = l & 15;      // sub-lane
    const int j   = 4 * b + w;   // owned h index
    const int row = grp * HID + j;

    unsigned long long* slot0 = ws;          // even tags
    unsigned long long* slot1 = ws + HID;    // odd tags

    __shared__ float4 wlds4[17 * TPB];   // 68 KB weight slice
    __shared__ float  hs[2][HID];        // double-buffered h
    __shared__ float  red[4];

    // ---- stage weights into LDS once ----
    {
        const float4* Whh4 = (const float4*)(W_hh + (size_t)row * HID);
        #pragma unroll
        for (int c = 0; c < 16; ++c)
            wlds4[c * TPB + t] = Whh4[sl + 16 * c];     // W_hh[row][64c+4sl..+3]
        wlds4[16 * TPB + t] = ((const float4*)(W_ih + (size_t)row * 64))[sl];
    }
    float bias[4];
    #pragma unroll
    for (int q = 0; q < 4; ++q) bias[q] = b_ih[q * HID + j] + b_hh[q * HID + j];

    const float4* xin4 = (const float4*)input;
    float c_state = 0.0f;
    __syncthreads();

    for (int s = 0; s < SEQ_LEN; ++s) {
        // ---- poll tagged slots for h_s (relaxed agent atomics, no fences) ----
        unsigned long long* rs = (s & 1) ? slot1 : slot0;
        const unsigned tag = (unsigned)s;
        unsigned long long v[4];
        bool rd[4] = {false, false, false, false};
        for (;;) {
            bool ok = true;
            #pragma unroll
            for (int k = 0; k < 4; ++k) {
                if (!rd[k]) {
                    v[k] = __hip_atomic_load(&rs[t + 256 * k], __ATOMIC_RELAXED,
                                             __HIP_MEMORY_SCOPE_AGENT);
                    rd[k] = ((unsigned)(v[k] >> 32) == tag);
                    ok &= rd[k];
                }
            }
            if (ok) break;
        }
        float* hsb = hs[s & 1];
        #pragma unroll
        for (int k = 0; k < 4; ++k)
            hsb[t + 256 * k] = __uint_as_float((unsigned)(v[k] & 0xffffffffull));

        // own x fragment straight from global (read-only, L1/L2 cacheable now)
        float4 x4 = xin4[s * 16 + sl];

        __syncthreads();   // the ONE barrier per step: hs staged by all waves

        // ---- 68 FMAs: weights b128 from LDS, h broadcast from LDS ----
        const float4* hs4 = (const float4*)hsb;
        float acc = 0.0f;
        #pragma unroll
        for (int c = 0; c < 16; ++c) {
            float4 wv = wlds4[c * TPB + t];
            float4 h4 = hs4[16 * c + sl];
            acc = fmaf(wv.x, h4.x, acc);
            acc = fmaf(wv.y, h4.y, acc);
            acc = fmaf(wv.z, h4.z, acc);
            acc = fmaf(wv.w, h4.w, acc);
        }
        {
            float4 wv = wlds4[16 * TPB + t];
            acc = fmaf(wv.x, x4.x, acc);
            acc = fmaf(wv.y, x4.y, acc);
            acc = fmaf(wv.z, x4.z, acc);
            acc = fmaf(wv.w, x4.w, acc);
        }

        // reduce across 16 lanes of the gate group
        acc += __shfl_xor(acc, 1);
        acc += __shfl_xor(acc, 2);
        acc += __shfl_xor(acc, 4);
        acc += __shfl_xor(acc, 8);

        float gi = __shfl(acc, 0)  + bias[0];
        float gf = __shfl(acc, 16) + bias[1];
        float gg = __shfl(acc, 32) + bias[2];
        float go = __shfl(acc, 48) + bias[3];

        float ig = fast_sigmoid(gi);
        float fg = fast_sigmoid(gf);
        float cg = fast_tanh(gg);
        float og = fast_sigmoid(go);
        c_state  = fmaf(fg, c_state, ig * cg);
        float hn = og * fast_tanh(c_state);

        // ---- publish h_{s+1}: ONE relaxed agent atomic store per wave ----
        if (l == 0) {
            unsigned long long pv =
                ((unsigned long long)(unsigned)(s + 1) << 32) |
                (unsigned long long)__float_as_uint(hn);
            unsigned long long* wsl = (s & 1) ? slot0 : slot1;   // (s+1)&1
            __hip_atomic_store(&wsl[j], pv, __ATOMIC_RELAXED,
                               __HIP_MEMORY_SCOPE_AGENT);
        }
        // no trailing barrier: hs double-buffered; skew bounded by slot deps
    }

    // ---- final projection: poll tag 4096 in buffer0, dot with W_lin ----
    if (b == 0) {
        const unsigned tag = (unsigned)SEQ_LEN;
        unsigned long long v[4];
        bool rd[4] = {false, false, false, false};
        for (;;) {
            bool ok = true;
            #pragma unroll
            for (int k = 0; k < 4; ++k) {
                if (!rd[k]) {
                    v[k] = __hip_atomic_load(&slot0[t + 256 * k], __ATOMIC_RELAXED,
                                             __HIP_MEMORY_SCOPE_AGENT);
                    rd[k] = ((unsigned)(v[k] >> 32) == tag);
                    ok &= rd[k];
                }
            }
            if (ok) break;
        }
        float p = 0.0f;
        #pragma unroll
        for (int k = 0; k < 4; ++k)
            p = fmaf(__uint_as_float((unsigned)(v[k] & 0xffffffffull)),
                     W_lin[t + 256 * k], p);
        #pragma unroll
        for (int m = 32; m >= 1; m >>= 1) p += __shfl_xor(p, m);
        if (l == 0) red[w] = p;
        __syncthreads();
        if (t == 0) out[0] = red[0] + red[1] + red[2] + red[3] + b_lin[0];
    }
}

extern "C" void kernel_launch(void* const* d_in, const int* in_sizes, int n_in,
                              void* d_out, int out_size, void* d_ws, size_t ws_size,
                              hipStream_t stream) {
    const float* input = (const float*)d_in[0];
    const float* W_ih  = (const float*)d_in[1];
    const float* W_hh  = (const float*)d_in[2];
    const float* b_ih  = (const float*)d_in[3];
    const float* b_hh  = (const float*)d_in[4];
    const float* W_lin = (const float*)d_in[5];
    const float* b_lin = (const float*)d_in[6];
    float* out = (float*)d_out;
    unsigned long long* ws = (unsigned long long*)d_ws;

    hipLaunchKernelGGL(lstm_init_kernel, dim3(1), dim3(256), 0, stream, ws);

    void* args[] = { (void*)&input, (void*)&W_ih, (void*)&W_hh, (void*)&b_ih,
                     (void*)&b_hh, (void*)&W_lin, (void*)&b_lin, (void*)&out, (void*)&ws };
    (void)hipLaunchCooperativeKernel((void*)lstm_persistent_kernel, dim3(NBLK), dim3(TPB),
                                     args, 0, stream);
}

// Round 6
// 8416.255 us; speedup vs baseline: 4.6282x; 1.3447x over previous
//
#include <hip/hip_runtime.h>

// LSTM: S=4096, I=64, H=1024, O=1, fp32.
// Persistent cooperative kernel, 128 blocks x 512 threads, weights in LDS.
// Protocol (round 5, validated): tagged 8-byte slots {tag:32|h_bits:32},
// relaxed agent-scope atomic store/load, tagged double buffer, zero fences.
// Round 6: shrink the arrival tail. 1024 independent 8B publishes (round 5,
// WRITE_SIZE showed 1024x32B sectors/step) -> 128 coalesced 64B line
// publishes (8 tagged words by lanes 0-7 of wave 0, handed off via LDS
// tagged words, no extra barrier). 4-way split accumulators; x-load hoisted.

#define SEQ_LEN 4096
#define HID 1024
#define NBLK 128
#define TPB 512
#define HPB 8      // h-indices per block (one per wave)

__device__ __forceinline__ float fast_sigmoid(float x) {
    return __builtin_amdgcn_rcpf(1.0f + __builtin_amdgcn_exp2f(-1.4426950408889634f * x));
}
__device__ __forceinline__ float fast_tanh(float x) {
    return fmaf(-2.0f, __builtin_amdgcn_rcpf(1.0f + __builtin_amdgcn_exp2f(2.8853900817779268f * x)), 1.0f);
}

// ws: unsigned long long slots[2][1024]. {tag<<32 | fp32 bits}. Zero-init:
// buffer0 tag0/val0 == h_0 = 0 (correct); buffer1 receives odd tags.
__global__ void lstm_init_kernel(unsigned long long* ws) {
    int t = threadIdx.x;
    #pragma unroll
    for (int k = 0; k < 8; ++k) ws[t + 256 * k] = 0ull;
}

__global__ __launch_bounds__(TPB, 1) void lstm_persistent_kernel(
    const float* __restrict__ input,   // [4096][64]
    const float* __restrict__ W_ih,    // [4096][64]
    const float* __restrict__ W_hh,    // [4096][1024]
    const float* __restrict__ b_ih,    // [4096]
    const float* __restrict__ b_hh,    // [4096]
    const float* __restrict__ W_lin,   // [1][1024]
    const float* __restrict__ b_lin,   // [1]
    float* __restrict__ out,           // [1]
    unsigned long long* __restrict__ ws)
{
    const int t   = threadIdx.x;
    const int b   = blockIdx.x;
    const int w   = t >> 6;      // wave in block (0..7)
    const int l   = t & 63;      // lane
    const int grp = l >> 4;      // gate q (i,f,g,o)
    const int sl  = l & 15;      // sub-lane within gate group
    const int j   = HPB * b + w; // owned h index
    const int row = grp * HID + j;

    unsigned long long* slot0 = ws;          // even tags
    unsigned long long* slot1 = ws + HID;    // odd tags

    __shared__ float4 wlds4[17 * TPB];                 // 136 KB weight slice
    __shared__ float  hs[2][HID];                      // double-buffered h (8 KB)
    __shared__ unsigned long long pub[HPB];            // tagged intra-block handoff
    __shared__ float  red[HPB];

    // ---- stage this block's 32 gate-rows into LDS (once) ----
    {
        const float4* Whh4 = (const float4*)(W_hh + (size_t)row * HID);
        #pragma unroll
        for (int c = 0; c < 16; ++c)
            wlds4[c * TPB + t] = Whh4[sl + 16 * c];     // W_hh[row][64c+4sl..+3]
        wlds4[16 * TPB + t] = ((const float4*)(W_ih + (size_t)row * 64))[sl];
    }
    float bias[4];
    #pragma unroll
    for (int q = 0; q < 4; ++q) bias[q] = b_ih[q * HID + j] + b_hh[q * HID + j];
    if (t < HPB) pub[t] = 0ull;

    const float4* xin4 = (const float4*)input;
    float c_state = 0.0f;
    __syncthreads();

    for (int s = 0; s < SEQ_LEN; ++s) {
        // issue x fragment load early (read-only, L1/L2-cacheable; no invalidates)
        float4 x4 = xin4[s * 16 + sl];

        // ---- poll 2 tagged slots (relaxed agent atomics, no fences) ----
        unsigned long long* rs = (s & 1) ? slot1 : slot0;
        const unsigned tag = (unsigned)s;
        unsigned long long v0, v1;
        bool r0 = false, r1 = false;
        do {
            if (!r0) { v0 = __hip_atomic_load(&rs[t      ], __ATOMIC_RELAXED, __HIP_MEMORY_SCOPE_AGENT);
                       r0 = ((unsigned)(v0 >> 32) == tag); }
            if (!r1) { v1 = __hip_atomic_load(&rs[t + 512], __ATOMIC_RELAXED, __HIP_MEMORY_SCOPE_AGENT);
                       r1 = ((unsigned)(v1 >> 32) == tag); }
        } while (!(r0 && r1));

        float* hsb = hs[s & 1];
        hsb[t      ] = __uint_as_float((unsigned)(v0 & 0xffffffffull));
        hsb[t + 512] = __uint_as_float((unsigned)(v1 & 0xffffffffull));

        __syncthreads();   // the ONE barrier per step: full h_s staged

        // ---- 68 FMAs, 4 split accumulators (break the dep chain) ----
        const float4* hs4 = (const float4*)hsb;
        float a0 = 0.f, a1 = 0.f, a2 = 0.f, a3 = 0.f;
        #pragma unroll
        for (int c = 0; c < 16; c += 4) {
            float4 wv0 = wlds4[(c    ) * TPB + t], h40 = hs4[16 * (c    ) + sl];
            float4 wv1 = wlds4[(c + 1) * TPB + t], h41 = hs4[16 * (c + 1) + sl];
            float4 wv2 = wlds4[(c + 2) * TPB + t], h42 = hs4[16 * (c + 2) + sl];
            float4 wv3 = wlds4[(c + 3) * TPB + t], h43 = hs4[16 * (c + 3) + sl];
            a0 = fmaf(wv0.x, h40.x, a0); a0 = fmaf(wv0.y, h40.y, a0);
            a0 = fmaf(wv0.z, h40.z, a0); a0 = fmaf(wv0.w, h40.w, a0);
            a1 = fmaf(wv1.x, h41.x, a1); a1 = fmaf(wv1.y, h41.y, a1);
            a1 = fmaf(wv1.z, h41.z, a1); a1 = fmaf(wv1.w, h41.w, a1);
            a2 = fmaf(wv2.x, h42.x, a2); a2 = fmaf(wv2.y, h42.y, a2);
            a2 = fmaf(wv2.z, h42.z, a2); a2 = fmaf(wv2.w, h42.w, a2);
            a3 = fmaf(wv3.x, h43.x, a3); a3 = fmaf(wv3.y, h43.y, a3);
            a3 = fmaf(wv3.z, h43.z, a3); a3 = fmaf(wv3.w, h43.w, a3);
        }
        {
            float4 wv = wlds4[16 * TPB + t];
            a0 = fmaf(wv.x, x4.x, a0); a1 = fmaf(wv.y, x4.y, a1);
            a2 = fmaf(wv.z, x4.z, a2); a3 = fmaf(wv.w, x4.w, a3);
        }
        float acc = (a0 + a1) + (a2 + a3);

        // reduce across 16 lanes of the gate group
        acc += __shfl_xor(acc, 1);
        acc += __shfl_xor(acc, 2);
        acc += __shfl_xor(acc, 4);
        acc += __shfl_xor(acc, 8);

        float gi = __shfl(acc, 0)  + bias[0];
        float gf = __shfl(acc, 16) + bias[1];
        float gg = __shfl(acc, 32) + bias[2];
        float go = __shfl(acc, 48) + bias[3];

        float ig = fast_sigmoid(gi);
        float fg = fast_sigmoid(gf);
        float cg = fast_tanh(gg);
        float og = fast_sigmoid(go);
        c_state  = fmaf(fg, c_state, ig * cg);
        float hn = og * fast_tanh(c_state);

        // ---- intra-block handoff: wave w lane 0 posts tagged hn to LDS ----
        const unsigned ntag = (unsigned)(s + 1);
        if (l == 0) {
            unsigned long long pv = ((unsigned long long)ntag << 32) |
                                    (unsigned long long)__float_as_uint(hn);
            __hip_atomic_store(&pub[w], pv, __ATOMIC_RELAXED, __HIP_MEMORY_SCOPE_WORKGROUP);
        }
        // ---- wave 0 lanes 0..7 gather the 8 words, publish one 64B line ----
        if (w == 0 && l < HPB) {
            unsigned long long pv;
            do {
                pv = __hip_atomic_load(&pub[l], __ATOMIC_RELAXED, __HIP_MEMORY_SCOPE_WORKGROUP);
            } while ((unsigned)(pv >> 32) != ntag);
            unsigned long long* wsl = (s & 1) ? slot0 : slot1;   // buffer (s+1)&1
            __hip_atomic_store(&wsl[HPB * b + l], pv, __ATOMIC_RELAXED, __HIP_MEMORY_SCOPE_AGENT);
        }
        // no trailing barrier: hs double-buffered; slot-tag deps bound skew
    }

    // ---- final projection: h_4096 (tag 4096, even -> slot0) . W_lin + b_lin ----
    if (b == 0) {
        const unsigned tag = (unsigned)SEQ_LEN;
        unsigned long long v0, v1;
        bool r0 = false, r1 = false;
        do {
            if (!r0) { v0 = __hip_atomic_load(&slot0[t      ], __ATOMIC_RELAXED, __HIP_MEMORY_SCOPE_AGENT);
                       r0 = ((unsigned)(v0 >> 32) == tag); }
            if (!r1) { v1 = __hip_atomic_load(&slot0[t + 512], __ATOMIC_RELAXED, __HIP_MEMORY_SCOPE_AGENT);
                       r1 = ((unsigned)(v1 >> 32) == tag); }
        } while (!(r0 && r1));
        float p = __uint_as_float((unsigned)(v0 & 0xffffffffull)) * W_lin[t] +
                  __uint_as_float((unsigned)(v1 & 0xffffffffull)) * W_lin[t + 512];
        #pragma unroll
        for (int m = 32; m >= 1; m >>= 1) p += __shfl_xor(p, m);
        if (l == 0) red[w] = p;
        __syncthreads();
        if (t == 0) {
            float r = 0.f;
            #pragma unroll
            for (int k = 0; k < HPB; ++k) r += red[k];
            out[0] = r + b_lin[0];
        }
    }
}

extern "C" void kernel_launch(void* const* d_in, const int* in_sizes, int n_in,
                              void* d_out, int out_size, void* d_ws, size_t ws_size,
                              hipStream_t stream) {
    const float* input = (const float*)d_in[0];
    const float* W_ih  = (const float*)d_in[1];
    const float* W_hh  = (const float*)d_in[2];
    const float* b_ih  = (const float*)d_in[3];
    const float* b_hh  = (const float*)d_in[4];
    const float* W_lin = (const float*)d_in[5];
    const float* b_lin = (const float*)d_in[6];
    float* out = (float*)d_out;
    unsigned long long* ws = (unsigned long long*)d_ws;

    hipLaunchKernelGGL(lstm_init_kernel, dim3(1), dim3(256), 0, stream, ws);

    void* args[] = { (void*)&input, (void*)&W_ih, (void*)&W_hh, (void*)&b_ih,
                     (void*)&b_hh, (void*)&W_lin, (void*)&b_lin, (void*)&out, (void*)&ws };
    (void)hipLaunchCooperativeKernel((void*)lstm_persistent_kernel, dim3(NBLK), dim3(TPB),
                                     args, 0, stream);
}